// Round 4
// baseline (118.048 us; speedup 1.0000x reference)
//
#include <hip/hip_runtime.h>

#define BB 16
#define QQ 1000
#define NH 8
#define LTOTAL 5440
#define MQ (BB*QQ)      // 16000
#define MV (BB*LTOTAL)  // 87040

typedef __bf16 bf16x8 __attribute__((ext_vector_type(8)));
typedef float  f32x4  __attribute__((ext_vector_type(4)));

__device__ __forceinline__ unsigned short f2bf(float f) {
  unsigned u = __builtin_bit_cast(unsigned, f);
  u += 0x7fffu + ((u >> 16) & 1u);
  return (unsigned short)(u >> 16);
}
__device__ __forceinline__ float b2f_lo(unsigned u) {
  return __builtin_bit_cast(float, u << 16);
}
__device__ __forceinline__ float b2f_hi(unsigned u) {
  return __builtin_bit_cast(float, u & 0xffff0000u);
}

__device__ __forceinline__ void gload16(const void* g, void* l) {
  __builtin_amdgcn_global_load_lds(
      (const __attribute__((address_space(1))) unsigned int*)g,
      (__attribute__((address_space(3))) unsigned int*)l, 16, 0, 0);
}

// ---------------- prep: all weight transposes (fp32->bf16) + bias concat -------
__global__ __launch_bounds__(256) void prep_k(const float* __restrict__ Wv,
                                              const float* __restrict__ Wo,
                                              const float* __restrict__ Wa,
                                              const float* __restrict__ Wout,
                                              const float* __restrict__ bo,
                                              const float* __restrict__ ba,
                                              unsigned short* __restrict__ Wvt,
                                              unsigned short* __restrict__ Wct,
                                              unsigned short* __restrict__ Wot,
                                              float* __restrict__ bcat) {
  int i = blockIdx.x * 256 + threadIdx.x;
  if (i < 65536) {
    int k = i >> 8, n = i & 255;
    Wvt[n * 256 + k] = f2bf(Wv[i]);
  } else if (i < 131072) {
    int j = i - 65536; int k = j >> 8, n = j & 255;
    Wct[n * 256 + k] = f2bf(Wo[j]);
  } else if (i < 163840) {
    int j = i - 131072; int k = j >> 7, n = j & 127;
    Wct[(256 + n) * 256 + k] = f2bf(Wa[j]);
  } else if (i < 229376) {
    int j = i - 163840; int k = j >> 8, n = j & 255;
    Wot[n * 256 + k] = f2bf(Wout[j]);
  } else if (i < 229760) {
    int j = i - 229376;
    bcat[j] = j < 256 ? bo[j] : ba[j - 256];
  }
}

// ---------------- pipelined MFMA GEMM: C[M,N] = A[M,256] @ Wt[N,256]^T + bias ---
// 128x128 tile, 4 waves (2x2 of 64x64), BK=32, NT=8 K-steps, double-buffered.
// One vmcnt(0) + one barrier per K-step; next-stage loads issued BEFORE compute
// so HBM latency hides under MFMA. AF32: A fp32 -> regs -> cvt bf16 -> ds_write
// (cvt deduplicated, A LDS halved to 8KB/stage). B (and bf16 A) staged via
// global_load_lds w=16 with source-side XOR swizzle matching the read swizzle.
template <bool AF32, bool OUTBF16>
__global__ __launch_bounds__(256) void gemm2_k(const void* __restrict__ Av,
                                               const unsigned short* __restrict__ Wt,
                                               const float* __restrict__ bias,
                                               void* __restrict__ C, int M, int N) {
  constexpr int K = 256;
  constexpr int NT = 8;
  __shared__ char lds[32768];
  char* As = lds;            // 2 x 8192 (bf16 128x32)
  char* Bs = lds + 16384;    // 2 x 8192

  int tid  = threadIdx.x;
  int wave = tid >> 6, lane = tid & 63;
  int ntiles = N >> 7;
  int mt = blockIdx.x / ntiles, nt = blockIdx.x - (blockIdx.x / ntiles) * ntiles;
  int r16 = lane & 15, kg = lane >> 4;
  int wm = wave >> 1, wn = wave & 1;

  // reg-staging identifiers (AF32): thread owns bf16 row arow, 32B half ahalf
  int arow = tid >> 1, ahalf = tid & 1;
  const float* Agp = (const float*)Av + (size_t)(mt * 128 + arow) * K + ahalf * 16;

  f32x4 a0, a1, a2, a3;   // staged A fp32 (16 floats)
  f32x4 acc[4][4] = {};

  auto loadA = [&](int t) {
    const float* s = Agp + t * 32;
    a0 = *(const f32x4*)(s + 0);
    a1 = *(const f32x4*)(s + 4);
    a2 = *(const f32x4*)(s + 8);
    a3 = *(const f32x4*)(s + 12);
  };
  auto writeA = [&](int buf) {
    bf16x8 g0, g1;
    g0[0]=(__bf16)a0[0]; g0[1]=(__bf16)a0[1]; g0[2]=(__bf16)a0[2]; g0[3]=(__bf16)a0[3];
    g0[4]=(__bf16)a1[0]; g0[5]=(__bf16)a1[1]; g0[6]=(__bf16)a1[2]; g0[7]=(__bf16)a1[3];
    g1[0]=(__bf16)a2[0]; g1[1]=(__bf16)a2[1]; g1[2]=(__bf16)a2[2]; g1[3]=(__bf16)a2[3];
    g1[4]=(__bf16)a3[0]; g1[5]=(__bf16)a3[1]; g1[6]=(__bf16)a3[2]; g1[7]=(__bf16)a3[3];
    char* Ad = As + buf * 8192;
    int sw = arow & 3;
    int u0 = ahalf * 2, u1 = u0 + 1;
    *(bf16x8*)(Ad + arow * 64 + ((u0 ^ sw) << 4)) = g0;
    *(bf16x8*)(Ad + arow * 64 + ((u1 ^ sw) << 4)) = g1;
  };
  auto stageLds = [&](int t, int buf) {
    int k0 = t * 32;
    char* Bd = Bs + buf * 8192;
#pragma unroll
    for (int j = 0; j < 2; j++) {
      int f = (j * 4 + wave) * 64 + lane;
      int row = f >> 2, u = f & 3;
      gload16(Wt + (size_t)(nt * 128 + row) * K + k0 + ((u ^ (row & 3)) << 3),
              Bd + (size_t)f * 16);
    }
    if (!AF32) {
      char* Ad = As + buf * 8192;
#pragma unroll
      for (int j = 0; j < 2; j++) {
        int f = (j * 4 + wave) * 64 + lane;
        int row = f >> 2, u = f & 3;
        gload16((const unsigned short*)Av + (size_t)(mt * 128 + row) * K + k0 +
                    ((u ^ (row & 3)) << 3),
                Ad + (size_t)f * 16);
      }
    }
  };
  auto compute = [&](int buf) {
    const char* Ad = As + buf * 8192;
    const char* Bd = Bs + buf * 8192;
    bf16x8 af[4], bfr[4];
#pragma unroll
    for (int mi = 0; mi < 4; mi++) {
      int row = wm * 64 + mi * 16 + r16;
      af[mi] = *(const bf16x8*)(Ad + row * 64 + ((kg ^ (row & 3)) << 4));
    }
#pragma unroll
    for (int ni = 0; ni < 4; ni++) {
      int row = wn * 64 + ni * 16 + r16;
      bfr[ni] = *(const bf16x8*)(Bd + row * 64 + ((kg ^ (row & 3)) << 4));
    }
#pragma unroll
    for (int mi = 0; mi < 4; mi++)
#pragma unroll
      for (int ni = 0; ni < 4; ni++)
        acc[mi][ni] = __builtin_amdgcn_mfma_f32_16x16x32_bf16(af[mi], bfr[ni], acc[mi][ni], 0, 0, 0);
  };

  // prologue: stage 0
  if (AF32) loadA(0);
  stageLds(0, 0);
  if (AF32) writeA(0);
  asm volatile("s_waitcnt vmcnt(0)" ::: "memory");
  __syncthreads();

#pragma unroll 2
  for (int t = 0; t < NT; ++t) {
    int buf = t & 1;
    if (t + 1 < NT) {
      if (AF32) loadA(t + 1);          // global->reg, latency hidden by compute
      stageLds(t + 1, buf ^ 1);        // B (and bf16 A) global->LDS async
    }
    compute(buf);
    if (t + 1 < NT) {
      if (AF32) writeA(buf ^ 1);       // cvt+ds_write (dep-wait on A loads)
      asm volatile("s_waitcnt vmcnt(0)" ::: "memory");  // B in LDS
      __syncthreads();
    }
  }

  int row0 = mt * 128 + wm * 64 + kg * 4;
  int col0 = nt * 128 + wn * 64 + r16;
#pragma unroll
  for (int ni = 0; ni < 4; ni++) {
    int col = col0 + ni * 16;
    float bs = bias[col];
#pragma unroll
    for (int mi = 0; mi < 4; mi++) {
#pragma unroll
      for (int j = 0; j < 4; j++) {
        int row = row0 + mi * 16 + j;
        float v = acc[mi][ni][j] + bs;
        if (OUTBF16) ((unsigned short*)C)[(size_t)row * N + col] = f2bf(v);
        else         ((float*)C)[(size_t)row * N + col] = v;
      }
    }
  }
}

// ---------------- sampling: softmax + bilinear gather-accumulate ----------------
__global__ __launch_bounds__(256) void sample_k(const float* __restrict__ offattn, // [MQ,384] f32
                                                const float* __restrict__ refp,    // [B,Q,4,2]
                                                const unsigned short* __restrict__ value, // [MV,256] bf16
                                                unsigned short* __restrict__ inter) {     // [MQ,256] bf16
  int t  = blockIdx.x * 256 + threadIdx.x;
  int bq = t >> 5;
  int h  = (t >> 2) & 7;
  int c0 = (t & 3) << 3;
  int b  = bq / QQ;

  const float* base = offattn + (size_t)bq * 384;

  float off[32];
  const float4* ob4 = (const float4*)(base + h * 32);
#pragma unroll
  for (int i = 0; i < 8; i++) {
    float4 v = ob4[i];
    off[4*i] = v.x; off[4*i+1] = v.y; off[4*i+2] = v.z; off[4*i+3] = v.w;
  }
  float lg[16];
  const float4* ab4 = (const float4*)(base + 256 + h * 16);
#pragma unroll
  for (int i = 0; i < 4; i++) {
    float4 v = ab4[i];
    lg[4*i] = v.x; lg[4*i+1] = v.y; lg[4*i+2] = v.z; lg[4*i+3] = v.w;
  }
  float m = -1e30f;
#pragma unroll
  for (int i = 0; i < 16; i++) m = fmaxf(m, lg[i]);
  float s = 0.f;
#pragma unroll
  for (int i = 0; i < 16; i++) { lg[i] = __expf(lg[i] - m); s += lg[i]; }
  float inv = 1.0f / s;

  float4 r01 = ((const float4*)(refp + (size_t)bq * 8))[0];
  float4 r23 = ((const float4*)(refp + (size_t)bq * 8))[1];
  float rxs[4] = {r01.x, r01.z, r23.x, r23.z};
  float rys[4] = {r01.y, r01.w, r23.y, r23.w};

  const unsigned short* vb = value + (size_t)b * (LTOTAL * 256) + h * 32 + c0;
  const int startL[4] = {0, 4096, 5120, 5376};

  float acc[8] = {};
#pragma unroll
  for (int lvl = 0; lvl < 4; lvl++) {
    int   Wi = 64 >> lvl;
    float Wf = (float)Wi;
    float px = rxs[lvl] * Wf - 0.5f;
    float py = rys[lvl] * Wf - 0.5f;
    const unsigned short* vl = vb + (size_t)startL[lvl] * 256;
#pragma unroll
    for (int pt = 0; pt < 4; pt++) {
      int p = lvl * 4 + pt;
      float wa = lg[p] * inv;
      float x = px + off[2*p];
      float y = py + off[2*p + 1];
      float xf = floorf(x), yf = floorf(y);
      float lx = x - xf, ly = y - yf;
      int x0 = (int)xf, y0 = (int)yf;
      float wx[2] = {1.f - lx, lx};
      float wy[2] = {1.f - ly, ly};
#pragma unroll
      for (int cy = 0; cy < 2; cy++) {
        int Y = y0 + cy;
        bool vy = (unsigned)Y < (unsigned)Wi;
        int Yc = min(max(Y, 0), Wi - 1);
#pragma unroll
        for (int cx = 0; cx < 2; cx++) {
          int X = x0 + cx;
          bool vx = (unsigned)X < (unsigned)Wi;
          int Xc = min(max(X, 0), Wi - 1);
          float w = (vx && vy) ? wa * wy[cy] * wx[cx] : 0.f;
          uint4 raw = *(const uint4*)(vl + (size_t)(Yc * Wi + Xc) * 256);
          acc[0] += w * b2f_lo(raw.x); acc[1] += w * b2f_hi(raw.x);
          acc[2] += w * b2f_lo(raw.y); acc[3] += w * b2f_hi(raw.y);
          acc[4] += w * b2f_lo(raw.z); acc[5] += w * b2f_hi(raw.z);
          acc[6] += w * b2f_lo(raw.w); acc[7] += w * b2f_hi(raw.w);
        }
      }
    }
  }

  unsigned o0 = f2bf(acc[0]) | ((unsigned)f2bf(acc[1]) << 16);
  unsigned o1 = f2bf(acc[2]) | ((unsigned)f2bf(acc[3]) << 16);
  unsigned o2 = f2bf(acc[4]) | ((unsigned)f2bf(acc[5]) << 16);
  unsigned o3 = f2bf(acc[6]) | ((unsigned)f2bf(acc[7]) << 16);
  uint4 st = {o0, o1, o2, o3};
  *(uint4*)(inter + (size_t)bq * 256 + h * 32 + c0) = st;
}

extern "C" void kernel_launch(void* const* d_in, const int* in_sizes, int n_in,
                              void* d_out, int out_size, void* d_ws, size_t ws_size,
                              hipStream_t stream) {
  const float* query  = (const float*)d_in[0];
  const float* refp   = (const float*)d_in[1];
  const float* inputf = (const float*)d_in[2];
  const float* Wv   = (const float*)d_in[5];
  const float* bv   = (const float*)d_in[6];
  const float* Wo   = (const float*)d_in[7];
  const float* bo   = (const float*)d_in[8];
  const float* Wa   = (const float*)d_in[9];
  const float* ba   = (const float*)d_in[10];
  const float* Wout = (const float*)d_in[11];
  const float* bout = (const float*)d_in[12];

  char* p = (char*)d_ws;
  auto alloc = [&](size_t bytes) -> char* {
    char* r = p;
    p += (bytes + 255) & ~(size_t)255;
    return r;
  };
  unsigned short* val   = (unsigned short*)alloc((size_t)MV * 256 * 2);
  unsigned short* Wvt   = (unsigned short*)alloc(256 * 256 * 2);
  unsigned short* Wct   = (unsigned short*)alloc(384 * 256 * 2);
  unsigned short* Wot   = (unsigned short*)alloc(256 * 256 * 2);
  float*          bcat  = (float*)alloc(384 * 4);
  float*          offattn = (float*)alloc((size_t)MQ * 384 * 4);
  unsigned short* inter = (unsigned short*)alloc((size_t)MQ * 256 * 2);

  prep_k<<<898, 256, 0, stream>>>(Wv, Wo, Wa, Wout, bo, ba, Wvt, Wct, Wot, bcat);

  // value = input_flatten @ Wv + bv (fp32 A, reg-staged cvt) -> bf16 [MV,256]
  gemm2_k<true, true><<<(MV / 128) * (256 / 128), 256, 0, stream>>>(
      (const void*)inputf, Wvt, bv, val, MV, 256);
  // offattn = query @ [Wo|Wa] + [bo|ba] -> fp32 [MQ,384]
  gemm2_k<true, false><<<(MQ / 128) * (384 / 128), 256, 0, stream>>>(
      (const void*)query, Wct, bcat, offattn, MQ, 384);
  // sampling -> inter bf16 [MQ,256]
  sample_k<<<MQ * 32 / 256, 256, 0, stream>>>(offattn, refp, val, inter);
  // out = inter @ Wout + bout -> fp32 d_out
  gemm2_k<false, false><<<(MQ / 128) * (256 / 128), 256, 0, stream>>>(
      (const void*)inter, Wot, bout, (float*)d_out, MQ, 256);
}

// Round 5
// 117.199 us; speedup vs baseline: 1.0072x; 1.0072x over previous
//
#include <hip/hip_runtime.h>

#define BB 16
#define QQ 1000
#define NH 8
#define LTOTAL 5440
#define MQ (BB*QQ)      // 16000
#define MV (BB*LTOTAL)  // 87040

typedef __bf16 bf16x8 __attribute__((ext_vector_type(8)));
typedef float  f32x4  __attribute__((ext_vector_type(4)));

template <int N> struct IC { static constexpr int v = N; };

__device__ __forceinline__ unsigned short f2bf(float f) {
  unsigned u = __builtin_bit_cast(unsigned, f);
  u += 0x7fffu + ((u >> 16) & 1u);
  return (unsigned short)(u >> 16);
}
__device__ __forceinline__ float b2f_lo(unsigned u) {
  return __builtin_bit_cast(float, u << 16);
}
__device__ __forceinline__ float b2f_hi(unsigned u) {
  return __builtin_bit_cast(float, u & 0xffff0000u);
}

__device__ __forceinline__ void gload16(const void* g, void* l) {
  __builtin_amdgcn_global_load_lds(
      (const __attribute__((address_space(1))) unsigned int*)g,
      (__attribute__((address_space(3))) unsigned int*)l, 16, 0, 0);
}

// ---------------- prep: weights -> staged granule layout (bf16) + bias concat --
// Staged layout per 128-col panel: granule g = (stage t)*512 + u*128 + row holds
// W[k = t*32+u*8 .. +8][n = panel*128+row] as 8 bf16. global_load_lds sources
// become linear; LDS reads become 2-way-bank-free.
__global__ __launch_bounds__(256) void prep_k(const float* __restrict__ Wv,
                                              const float* __restrict__ Wo,
                                              const float* __restrict__ Wa,
                                              const float* __restrict__ Wout,
                                              const float* __restrict__ bo,
                                              const float* __restrict__ ba,
                                              unsigned short* __restrict__ WvS,  // 2 panels
                                              unsigned short* __restrict__ WcS,  // 3 panels
                                              unsigned short* __restrict__ WoS,  // 2 panels
                                              float* __restrict__ bcat) {
  int i = blockIdx.x * 256 + threadIdx.x;
  if (i < 28672) {
    const float* src;
    unsigned short* dst;
    int g, srcN;
    if (i < 8192)       { g = i;         dst = WvS; src = Wv;   srcN = 256; }
    else if (i < 20480) { g = i - 8192;  dst = WcS; src = Wo;   srcN = 256; }
    else                { g = i - 20480; dst = WoS; src = Wout; srcN = 256; }
    int panel = g >> 12, t = (g >> 9) & 7, u = (g >> 7) & 3, row = g & 127;
    int kbase = t * 32 + u * 8;
    int n = panel * 128 + row;
    if (dst == WcS && panel == 2) { src = Wa; srcN = 128; n = row; }
    bf16x8 r;
#pragma unroll
    for (int e = 0; e < 8; e++) r[e] = (__bf16)src[(size_t)(kbase + e) * srcN + n];
    *(bf16x8*)(dst + (size_t)g * 8) = r;
  } else if (i < 29056) {
    int j = i - 28672;
    bcat[j] = j < 256 ? bo[j] : ba[j - 256];
  }
}

// ---------------- depth-2 pipelined MFMA GEMM --------------------------------
// C[M,N] = A[M,256] @ W^T + bias. 128x128 tile, 4 waves (2x2 of 64x64), BK=32.
// Per iter t: issue stage(t+2); compute(t); vmcnt(STEADY) -> stage(t+1) landed
// (issued a full iteration earlier => wait ~0); writeA; one barrier. B (and
// bf16-A) come from PRE-STAGED layout via global_load_lds (linear source,
// conflict-free [u][row] LDS). fp32-A is reg-staged + converted + ds_written.
template <bool AF32, bool OUTBF16>
__global__ __launch_bounds__(256) void gemm3_k(const void* __restrict__ Av,
                                               const unsigned short* __restrict__ WS,
                                               const float* __restrict__ bias,
                                               void* __restrict__ C, int M, int N) {
  constexpr int K = 256, NT = 8;
  constexpr int STEADY = AF32 ? 6 : 4;
  constexpr int ASL = AF32 ? 2 : 3;
  __shared__ char lds[(ASL + 3) * 8192];
  char* As = lds;
  char* Bs = lds + ASL * 8192;

  int tid = threadIdx.x, wave = tid >> 6, lane = tid & 63;
  int ntiles = N >> 7;
  int mt = blockIdx.x / ntiles, nt = blockIdx.x - (blockIdx.x / ntiles) * ntiles;
  int r16 = lane & 15, kg = lane >> 4;
  int wm = wave >> 1, wn = wave & 1;
  int arow = tid >> 1, ahalf = tid & 1;

  const unsigned short* Bpanel = WS + (size_t)nt * (NT * 512 * 8);
  const unsigned short* Apanel = (const unsigned short*)Av + (size_t)mt * (NT * 512 * 8);
  const float* Ag32 = (const float*)Av + (size_t)(mt * 128 + arow) * K + ahalf * 16;

  f32x4 ar[2][4];
  f32x4 acc[4][4] = {};

  auto stageB = [&](int s) {
    char* Bd = Bs + (s % 3) * 8192;
    const unsigned short* sp = Bpanel + (size_t)s * 512 * 8;
#pragma unroll
    for (int j = 0; j < 2; j++) {
      int f = (j * 4 + wave) * 64 + lane;
      gload16(sp + f * 8, Bd + f * 16);
    }
  };
  auto stageA16 = [&](int s) {
    char* Ad = As + (s % 3) * 8192;
    const unsigned short* sp = Apanel + (size_t)s * 512 * 8;
#pragma unroll
    for (int j = 0; j < 2; j++) {
      int f = (j * 4 + wave) * 64 + lane;
      gload16(sp + f * 8, Ad + f * 16);
    }
  };
  auto loadA32 = [&](int s, f32x4* r) {
    const float* sp = Ag32 + s * 32;
    r[0] = *(const f32x4*)(sp);
    r[1] = *(const f32x4*)(sp + 4);
    r[2] = *(const f32x4*)(sp + 8);
    r[3] = *(const f32x4*)(sp + 12);
  };
  auto writeA32 = [&](int slot, f32x4* r) {
    bf16x8 g0, g1;
    g0[0]=(__bf16)r[0][0]; g0[1]=(__bf16)r[0][1]; g0[2]=(__bf16)r[0][2]; g0[3]=(__bf16)r[0][3];
    g0[4]=(__bf16)r[1][0]; g0[5]=(__bf16)r[1][1]; g0[6]=(__bf16)r[1][2]; g0[7]=(__bf16)r[1][3];
    g1[0]=(__bf16)r[2][0]; g1[1]=(__bf16)r[2][1]; g1[2]=(__bf16)r[2][2]; g1[3]=(__bf16)r[2][3];
    g1[4]=(__bf16)r[3][0]; g1[5]=(__bf16)r[3][1]; g1[6]=(__bf16)r[3][2]; g1[7]=(__bf16)r[3][3];
    char* Ad = As + slot * 8192;
    int u0 = ahalf * 2;
    *(bf16x8*)(Ad + (((u0    ) * 128 + arow) << 4)) = g0;
    *(bf16x8*)(Ad + (((u0 + 1) * 128 + arow) << 4)) = g1;
  };
  auto compute = [&](int sa, int sb) {
    const char* Ad = As + sa * 8192;
    const char* Bd = Bs + sb * 8192;
    bf16x8 af[4], bq[4];
#pragma unroll
    for (int mi = 0; mi < 4; mi++) {
      int row = wm * 64 + mi * 16 + r16;
      af[mi] = *(const bf16x8*)(Ad + ((kg * 128 + row) << 4));
    }
#pragma unroll
    for (int ni = 0; ni < 4; ni++) {
      int row = wn * 64 + ni * 16 + r16;
      bq[ni] = *(const bf16x8*)(Bd + ((kg * 128 + row) << 4));
    }
#pragma unroll
    for (int mi = 0; mi < 4; mi++)
#pragma unroll
      for (int ni = 0; ni < 4; ni++)
        acc[mi][ni] = __builtin_amdgcn_mfma_f32_16x16x32_bf16(af[mi], bq[ni], acc[mi][ni], 0, 0, 0);
  };

  // prologue: issue stages 0,1; wait stage0; publish A0
  if (AF32) { loadA32(0, ar[0]); stageB(0); loadA32(1, ar[1]); stageB(1); }
  else      { stageA16(0); stageB(0); stageA16(1); stageB(1); }
  asm volatile("s_waitcnt vmcnt(%0)" :: "i"(STEADY) : "memory");
  if (AF32) writeA32(0, ar[0]);
  __syncthreads();

  auto step = [&](auto TC) {
    constexpr int t = decltype(TC)::v;
    if constexpr (t + 2 < NT) {
      if (AF32) loadA32(t + 2, ar[(t + 2) & 1]);
      else      stageA16(t + 2);
      stageB(t + 2);
    }
    compute(AF32 ? (t & 1) : (t % 3), t % 3);
    if constexpr (t + 1 < NT) {
      if constexpr (t + 2 < NT)
        asm volatile("s_waitcnt vmcnt(%0)" :: "i"(STEADY) : "memory");
      else
        asm volatile("s_waitcnt vmcnt(0)" ::: "memory");
      if (AF32) writeA32((t + 1) & 1, ar[(t + 1) & 1]);
      __syncthreads();
    }
  };
  step(IC<0>{}); step(IC<1>{}); step(IC<2>{}); step(IC<3>{});
  step(IC<4>{}); step(IC<5>{}); step(IC<6>{}); step(IC<7>{});

  int row0 = mt * 128 + wm * 64 + kg * 4;
  int col0 = nt * 128 + wn * 64 + r16;
#pragma unroll
  for (int ni = 0; ni < 4; ni++) {
    int col = col0 + ni * 16;
    float bs = bias[col];
#pragma unroll
    for (int mi = 0; mi < 4; mi++) {
#pragma unroll
      for (int j = 0; j < 4; j++) {
        int row = row0 + mi * 16 + j;
        float v = acc[mi][ni][j] + bs;
        if (OUTBF16) ((unsigned short*)C)[(size_t)row * N + col] = f2bf(v);
        else         ((float*)C)[(size_t)row * N + col] = v;
      }
    }
  }
}

// ---------------- sampling: softmax + bilinear gather-accumulate ----------------
// 32 lanes per (b,q); lane owns 8 channels of one head; 16B gathers. Writes
// inter in the STAGED layout so the final GEMM can global_load_lds it linearly.
__global__ __launch_bounds__(256) void sample_k(const float* __restrict__ offattn, // [MQ,384] f32
                                                const float* __restrict__ refp,    // [B,Q,4,2]
                                                const unsigned short* __restrict__ value, // [MV,256] bf16
                                                unsigned short* __restrict__ interS) {    // staged
  int t  = blockIdx.x * 256 + threadIdx.x;
  int bq = t >> 5;
  int h  = (t >> 2) & 7;
  int c0 = (t & 3) << 3;
  int b  = bq / QQ;

  const float* base = offattn + (size_t)bq * 384;

  float off[32];
  const float4* ob4 = (const float4*)(base + h * 32);
#pragma unroll
  for (int i = 0; i < 8; i++) {
    float4 v = ob4[i];
    off[4*i] = v.x; off[4*i+1] = v.y; off[4*i+2] = v.z; off[4*i+3] = v.w;
  }
  float lg[16];
  const float4* ab4 = (const float4*)(base + 256 + h * 16);
#pragma unroll
  for (int i = 0; i < 4; i++) {
    float4 v = ab4[i];
    lg[4*i] = v.x; lg[4*i+1] = v.y; lg[4*i+2] = v.z; lg[4*i+3] = v.w;
  }
  float m = -1e30f;
#pragma unroll
  for (int i = 0; i < 16; i++) m = fmaxf(m, lg[i]);
  float s = 0.f;
#pragma unroll
  for (int i = 0; i < 16; i++) { lg[i] = __expf(lg[i] - m); s += lg[i]; }
  float inv = 1.0f / s;

  float4 r01 = ((const float4*)(refp + (size_t)bq * 8))[0];
  float4 r23 = ((const float4*)(refp + (size_t)bq * 8))[1];
  float rxs[4] = {r01.x, r01.z, r23.x, r23.z};
  float rys[4] = {r01.y, r01.w, r23.y, r23.w};

  const unsigned short* vb = value + (size_t)b * (LTOTAL * 256) + h * 32 + c0;
  const int startL[4] = {0, 4096, 5120, 5376};

  float acc[8] = {};
#pragma unroll
  for (int lvl = 0; lvl < 4; lvl++) {
    int   Wi = 64 >> lvl;
    float Wf = (float)Wi;
    float px = rxs[lvl] * Wf - 0.5f;
    float py = rys[lvl] * Wf - 0.5f;
    const unsigned short* vl = vb + (size_t)startL[lvl] * 256;
#pragma unroll
    for (int pt = 0; pt < 4; pt++) {
      int p = lvl * 4 + pt;
      float wa = lg[p] * inv;
      float x = px + off[2*p];
      float y = py + off[2*p + 1];
      float xf = floorf(x), yf = floorf(y);
      float lx = x - xf, ly = y - yf;
      int x0 = (int)xf, y0 = (int)yf;
      float wx[2] = {1.f - lx, lx};
      float wy[2] = {1.f - ly, ly};
#pragma unroll
      for (int cy = 0; cy < 2; cy++) {
        int Y = y0 + cy;
        bool vy = (unsigned)Y < (unsigned)Wi;
        int Yc = min(max(Y, 0), Wi - 1);
#pragma unroll
        for (int cx = 0; cx < 2; cx++) {
          int X = x0 + cx;
          bool vx = (unsigned)X < (unsigned)Wi;
          int Xc = min(max(X, 0), Wi - 1);
          float w = (vx && vy) ? wa * wy[cy] * wx[cx] : 0.f;
          uint4 raw = *(const uint4*)(vl + (size_t)(Yc * Wi + Xc) * 256);
          acc[0] += w * b2f_lo(raw.x); acc[1] += w * b2f_hi(raw.x);
          acc[2] += w * b2f_lo(raw.y); acc[3] += w * b2f_hi(raw.y);
          acc[4] += w * b2f_lo(raw.z); acc[5] += w * b2f_hi(raw.z);
          acc[6] += w * b2f_lo(raw.w); acc[7] += w * b2f_hi(raw.w);
        }
      }
    }
  }

  unsigned o0 = f2bf(acc[0]) | ((unsigned)f2bf(acc[1]) << 16);
  unsigned o1 = f2bf(acc[2]) | ((unsigned)f2bf(acc[3]) << 16);
  unsigned o2 = f2bf(acc[4]) | ((unsigned)f2bf(acc[5]) << 16);
  unsigned o3 = f2bf(acc[6]) | ((unsigned)f2bf(acc[7]) << 16);
  uint4 st = {o0, o1, o2, o3};

  // staged layout: tile mt = bq>>7, row = bq&127, stage = h, u = c0>>3
  int mtile = bq >> 7, row = bq & 127;
  size_t goff = (((size_t)(mtile * 8 + h)) * 512 + (c0 >> 3) * 128 + row) * 8;
  *(uint4*)(interS + goff) = st;
}

extern "C" void kernel_launch(void* const* d_in, const int* in_sizes, int n_in,
                              void* d_out, int out_size, void* d_ws, size_t ws_size,
                              hipStream_t stream) {
  const float* query  = (const float*)d_in[0];
  const float* refp   = (const float*)d_in[1];
  const float* inputf = (const float*)d_in[2];
  const float* Wv   = (const float*)d_in[5];
  const float* bv   = (const float*)d_in[6];
  const float* Wo   = (const float*)d_in[7];
  const float* bo   = (const float*)d_in[8];
  const float* Wa   = (const float*)d_in[9];
  const float* ba   = (const float*)d_in[10];
  const float* Wout = (const float*)d_in[11];
  const float* bout = (const float*)d_in[12];

  char* p = (char*)d_ws;
  auto alloc = [&](size_t bytes) -> char* {
    char* r = p;
    p += (bytes + 255) & ~(size_t)255;
    return r;
  };
  unsigned short* val   = (unsigned short*)alloc((size_t)MV * 256 * 2);
  unsigned short* WvS   = (unsigned short*)alloc(2 * 4096 * 8 * 2);
  unsigned short* WcS   = (unsigned short*)alloc(3 * 4096 * 8 * 2);
  unsigned short* WoS   = (unsigned short*)alloc(2 * 4096 * 8 * 2);
  float*          bcat  = (float*)alloc(384 * 4);
  float*          offattn = (float*)alloc((size_t)MQ * 384 * 4);
  unsigned short* interS = (unsigned short*)alloc((size_t)MQ * 256 * 2);

  prep_k<<<114, 256, 0, stream>>>(Wv, Wo, Wa, Wout, bo, ba, WvS, WcS, WoS, bcat);

  // value = input_flatten @ Wv + bv (fp32 A reg-staged) -> bf16 [MV,256]
  gemm3_k<true, true><<<(MV / 128) * 2, 256, 0, stream>>>(
      (const void*)inputf, WvS, bv, val, MV, 256);
  // offattn = query @ [Wo|Wa] + [bo|ba] -> fp32 [MQ,384]
  gemm3_k<true, false><<<(MQ / 128) * 3, 256, 0, stream>>>(
      (const void*)query, WcS, bcat, offattn, MQ, 384);
  // sampling -> interS (staged bf16)
  sample_k<<<MQ * 32 / 256, 256, 0, stream>>>(offattn, refp, val, interS);
  // out = interS @ Wout + bout -> fp32 d_out
  gemm3_k<false, false><<<(MQ / 128) * 2, 256, 0, stream>>>(
      (const void*)interS, WoS, bout, (float*)d_out, MQ, 256);
}

// Round 6
// 111.270 us; speedup vs baseline: 1.0609x; 1.0533x over previous
//
#include <hip/hip_runtime.h>

#define BB 16
#define QQ 1000
#define NH 8
#define LTOTAL 5440
#define MQ (BB*QQ)      // 16000
#define MV (BB*LTOTAL)  // 87040

typedef __bf16 bf16x8 __attribute__((ext_vector_type(8)));
typedef float  f32x4  __attribute__((ext_vector_type(4)));

template <int N> struct IC { static constexpr int v = N; };

__device__ __forceinline__ unsigned short f2bf(float f) {
  unsigned u = __builtin_bit_cast(unsigned, f);
  u += 0x7fffu + ((u >> 16) & 1u);
  return (unsigned short)(u >> 16);
}
__device__ __forceinline__ float b2f_lo(unsigned u) {
  return __builtin_bit_cast(float, u << 16);
}
__device__ __forceinline__ float b2f_hi(unsigned u) {
  return __builtin_bit_cast(float, u & 0xffff0000u);
}

__device__ __forceinline__ void gload16(const void* g, void* l) {
  __builtin_amdgcn_global_load_lds(
      (const __attribute__((address_space(1))) unsigned int*)g,
      (__attribute__((address_space(3))) unsigned int*)l, 16, 0, 0);
}

// lgkmcnt(0) for ds_write visibility + raw barrier; vmcnt deliberately NOT
// drained (loads stay in flight across the barrier — the whole point).
__device__ __forceinline__ void pipe_barrier() {
  asm volatile("s_waitcnt lgkmcnt(0)" ::: "memory");
  __builtin_amdgcn_sched_barrier(0);
  __builtin_amdgcn_s_barrier();
  __builtin_amdgcn_sched_barrier(0);
}

// ---------------- prep: weights -> staged granule layout (bf16) + bias concat --
__global__ __launch_bounds__(256) void prep_k(const float* __restrict__ Wv,
                                              const float* __restrict__ Wo,
                                              const float* __restrict__ Wa,
                                              const float* __restrict__ Wout,
                                              const float* __restrict__ bo,
                                              const float* __restrict__ ba,
                                              unsigned short* __restrict__ WvS,  // 2 panels
                                              unsigned short* __restrict__ WcS,  // 3 panels
                                              unsigned short* __restrict__ WoS,  // 2 panels
                                              float* __restrict__ bcat) {
  int i = blockIdx.x * 256 + threadIdx.x;
  if (i < 28672) {
    const float* src;
    unsigned short* dst;
    int g, srcN;
    if (i < 8192)       { g = i;         dst = WvS; src = Wv;   srcN = 256; }
    else if (i < 20480) { g = i - 8192;  dst = WcS; src = Wo;   srcN = 256; }
    else                { g = i - 20480; dst = WoS; src = Wout; srcN = 256; }
    int panel = g >> 12, t = (g >> 9) & 7, u = (g >> 7) & 3, row = g & 127;
    int kbase = t * 32 + u * 8;
    int n = panel * 128 + row;
    if (dst == WcS && panel == 2) { src = Wa; srcN = 128; n = row; }
    bf16x8 r;
#pragma unroll
    for (int e = 0; e < 8; e++) r[e] = (__bf16)src[(size_t)(kbase + e) * srcN + n];
    *(bf16x8*)(dst + (size_t)g * 8) = r;
  } else if (i < 29056) {
    int j = i - 28672;
    bcat[j] = j < 256 ? bo[j] : ba[j - 256];
  }
}

// ---------------- depth-2 pipelined MFMA GEMM, raw-barrier edition ------------
// C[M,N] = A[M,256] @ W^T + bias. 128x128 tile, 4 waves (2x2 of 64x64), BK=32.
// Per iter t: issue stage(t+2); compute(t); vmcnt(STEADY) waits only stage(t+1)
// (issued a full iteration earlier); ds_write A; lgkmcnt(0)+s_barrier (raw —
// __syncthreads would re-drain vmcnt to 0 and kill the pipeline).
template <bool AF32, bool OUTBF16>
__global__ __launch_bounds__(256) void gemm3_k(const void* __restrict__ Av,
                                               const unsigned short* __restrict__ WS,
                                               const float* __restrict__ bias,
                                               void* __restrict__ C, int M, int N) {
  constexpr int K = 256, NT = 8;
  constexpr int STEADY = AF32 ? 6 : 4;
  constexpr int ASL = AF32 ? 2 : 3;
  __shared__ char lds[(ASL + 3) * 8192];
  char* As = lds;
  char* Bs = lds + ASL * 8192;

  int tid = threadIdx.x, wave = tid >> 6, lane = tid & 63;
  int ntiles = N >> 7;
  int mt = blockIdx.x / ntiles, nt = blockIdx.x - (blockIdx.x / ntiles) * ntiles;
  int r16 = lane & 15, kg = lane >> 4;
  int wm = wave >> 1, wn = wave & 1;
  int arow = tid >> 1, ahalf = tid & 1;

  const unsigned short* Bpanel = WS + (size_t)nt * (NT * 512 * 8);
  const unsigned short* Apanel = (const unsigned short*)Av + (size_t)mt * (NT * 512 * 8);
  const float* Ag32 = (const float*)Av + (size_t)(mt * 128 + arow) * K + ahalf * 16;

  f32x4 ar[2][4];
  f32x4 acc[4][4] = {};

  auto stageB = [&](int s) {
    char* Bd = Bs + (s % 3) * 8192;
    const unsigned short* sp = Bpanel + (size_t)s * 512 * 8;
#pragma unroll
    for (int j = 0; j < 2; j++) {
      int f = (j * 4 + wave) * 64 + lane;
      gload16(sp + f * 8, Bd + f * 16);
    }
  };
  auto stageA16 = [&](int s) {
    char* Ad = As + (s % 3) * 8192;
    const unsigned short* sp = Apanel + (size_t)s * 512 * 8;
#pragma unroll
    for (int j = 0; j < 2; j++) {
      int f = (j * 4 + wave) * 64 + lane;
      gload16(sp + f * 8, Ad + f * 16);
    }
  };
  auto loadA32 = [&](int s, f32x4* r) {
    const float* sp = Ag32 + s * 32;
    r[0] = *(const f32x4*)(sp);
    r[1] = *(const f32x4*)(sp + 4);
    r[2] = *(const f32x4*)(sp + 8);
    r[3] = *(const f32x4*)(sp + 12);
  };
  auto writeA32 = [&](int slot, f32x4* r) {
    bf16x8 g0, g1;
    g0[0]=(__bf16)r[0][0]; g0[1]=(__bf16)r[0][1]; g0[2]=(__bf16)r[0][2]; g0[3]=(__bf16)r[0][3];
    g0[4]=(__bf16)r[1][0]; g0[5]=(__bf16)r[1][1]; g0[6]=(__bf16)r[1][2]; g0[7]=(__bf16)r[1][3];
    g1[0]=(__bf16)r[2][0]; g1[1]=(__bf16)r[2][1]; g1[2]=(__bf16)r[2][2]; g1[3]=(__bf16)r[2][3];
    g1[4]=(__bf16)r[3][0]; g1[5]=(__bf16)r[3][1]; g1[6]=(__bf16)r[3][2]; g1[7]=(__bf16)r[3][3];
    char* Ad = As + slot * 8192;
    int u0 = ahalf * 2;
    *(bf16x8*)(Ad + (((u0    ) * 128 + arow) << 4)) = g0;
    *(bf16x8*)(Ad + (((u0 + 1) * 128 + arow) << 4)) = g1;
  };
  auto compute = [&](int sa, int sb) {
    const char* Ad = As + sa * 8192;
    const char* Bd = Bs + sb * 8192;
    bf16x8 af[4], bq[4];
#pragma unroll
    for (int mi = 0; mi < 4; mi++) {
      int row = wm * 64 + mi * 16 + r16;
      af[mi] = *(const bf16x8*)(Ad + ((kg * 128 + row) << 4));
    }
#pragma unroll
    for (int ni = 0; ni < 4; ni++) {
      int row = wn * 64 + ni * 16 + r16;
      bq[ni] = *(const bf16x8*)(Bd + ((kg * 128 + row) << 4));
    }
#pragma unroll
    for (int mi = 0; mi < 4; mi++)
#pragma unroll
      for (int ni = 0; ni < 4; ni++)
        acc[mi][ni] = __builtin_amdgcn_mfma_f32_16x16x32_bf16(af[mi], bq[ni], acc[mi][ni], 0, 0, 0);
  };

  // prologue: issue stages 0,1; wait stage0 only; publish A0
  if (AF32) { loadA32(0, ar[0]); stageB(0); loadA32(1, ar[1]); stageB(1); }
  else      { stageA16(0); stageB(0); stageA16(1); stageB(1); }
  asm volatile("s_waitcnt vmcnt(%0)" :: "i"(STEADY) : "memory");
  if (AF32) writeA32(0, ar[0]);
  pipe_barrier();

  auto step = [&](auto TC) {
    constexpr int t = decltype(TC)::v;
    if constexpr (t + 2 < NT) {
      if (AF32) loadA32(t + 2, ar[(t + 2) & 1]);
      else      stageA16(t + 2);
      stageB(t + 2);
    }
    compute(AF32 ? (t & 1) : (t % 3), t % 3);
    if constexpr (t + 1 < NT) {
      if constexpr (t + 2 < NT)
        asm volatile("s_waitcnt vmcnt(%0)" :: "i"(STEADY) : "memory");
      else
        asm volatile("s_waitcnt vmcnt(0)" ::: "memory");
      if (AF32) writeA32((t + 1) & 1, ar[(t + 1) & 1]);
      pipe_barrier();
    }
  };
  step(IC<0>{}); step(IC<1>{}); step(IC<2>{}); step(IC<3>{});
  step(IC<4>{}); step(IC<5>{}); step(IC<6>{}); step(IC<7>{});

  int row0 = mt * 128 + wm * 64 + kg * 4;
  int col0 = nt * 128 + wn * 64 + r16;
#pragma unroll
  for (int ni = 0; ni < 4; ni++) {
    int col = col0 + ni * 16;
    float bs = bias[col];
#pragma unroll
    for (int mi = 0; mi < 4; mi++) {
#pragma unroll
      for (int j = 0; j < 4; j++) {
        int row = row0 + mi * 16 + j;
        float v = acc[mi][ni][j] + bs;
        if (OUTBF16) ((unsigned short*)C)[(size_t)row * N + col] = f2bf(v);
        else         ((float*)C)[(size_t)row * N + col] = v;
      }
    }
  }
}

// ---------------- sampling: softmax + bilinear gather-accumulate ----------------
// 32 lanes per (b,q); lane owns 8 channels of one head. Per level: compute all
// 16 (weight, offset) corner descriptors (static arrays), THEN issue all 16
// uint4 gathers, THEN FMA — gives the compiler 16-deep MLP per wave.
// __launch_bounds__(256,3): ~170 VGPR budget, 12 waves/CU.
__global__ __launch_bounds__(256, 3) void sample_k(const float* __restrict__ offattn, // [MQ,384]
                                                   const float* __restrict__ refp,    // [B,Q,4,2]
                                                   const unsigned short* __restrict__ value,
                                                   unsigned short* __restrict__ interS) {
  int t  = blockIdx.x * 256 + threadIdx.x;
  int bq = t >> 5;
  int h  = (t >> 2) & 7;
  int c0 = (t & 3) << 3;
  int b  = bq / QQ;

  const float* base = offattn + (size_t)bq * 384;

  float lg[16];
  const float4* ab4 = (const float4*)(base + 256 + h * 16);
#pragma unroll
  for (int i = 0; i < 4; i++) {
    float4 v = ab4[i];
    lg[4*i] = v.x; lg[4*i+1] = v.y; lg[4*i+2] = v.z; lg[4*i+3] = v.w;
  }
  float m = -1e30f;
#pragma unroll
  for (int i = 0; i < 16; i++) m = fmaxf(m, lg[i]);
  float s = 0.f;
#pragma unroll
  for (int i = 0; i < 16; i++) { lg[i] = __expf(lg[i] - m); s += lg[i]; }
  float inv = 1.0f / s;

  float4 r01 = ((const float4*)(refp + (size_t)bq * 8))[0];
  float4 r23 = ((const float4*)(refp + (size_t)bq * 8))[1];
  float rxs[4] = {r01.x, r01.z, r23.x, r23.z};
  float rys[4] = {r01.y, r01.w, r23.y, r23.w};

  const unsigned short* vb = value + (size_t)b * (LTOTAL * 256) + h * 32 + c0;
  const int startL[4] = {0, 4096, 5120, 5376};

  float acc[8] = {};
#pragma unroll
  for (int lvl = 0; lvl < 4; lvl++) {
    int   Wi = 64 >> lvl;
    float Wf = (float)Wi;
    float px = rxs[lvl] * Wf - 0.5f;
    float py = rys[lvl] * Wf - 0.5f;
    const unsigned short* vl = vb + (size_t)startL[lvl] * 256;

    const float4* ob4 = (const float4*)(base + h * 32 + lvl * 8);
    float4 o01 = ob4[0], o23 = ob4[1];
    float oxs[4] = {o01.x, o01.z, o23.x, o23.z};
    float oys[4] = {o01.y, o01.w, o23.y, o23.w};

    float cw[16];
    int   coff[16];
#pragma unroll
    for (int pt = 0; pt < 4; pt++) {
      float wa = lg[lvl * 4 + pt] * inv;
      float x = px + oxs[pt];
      float y = py + oys[pt];
      float xf = floorf(x), yf = floorf(y);
      float lx = x - xf, ly = y - yf;
      int x0 = (int)xf, y0 = (int)yf;
      float wx[2] = {1.f - lx, lx};
      float wy[2] = {1.f - ly, ly};
#pragma unroll
      for (int cy = 0; cy < 2; cy++) {
        int Y = y0 + cy;
        bool vy = (unsigned)Y < (unsigned)Wi;
        int Yc = min(max(Y, 0), Wi - 1);
#pragma unroll
        for (int cx = 0; cx < 2; cx++) {
          int X = x0 + cx;
          bool vx = (unsigned)X < (unsigned)Wi;
          int Xc = min(max(X, 0), Wi - 1);
          int c = pt * 4 + cy * 2 + cx;
          cw[c]   = (vx && vy) ? wa * wy[cy] * wx[cx] : 0.f;
          coff[c] = (Yc * Wi + Xc) * 256;
        }
      }
    }
    uint4 raw[16];
#pragma unroll
    for (int c = 0; c < 16; c++) raw[c] = *(const uint4*)(vl + coff[c]);
#pragma unroll
    for (int c = 0; c < 16; c++) {
      float w = cw[c];
      acc[0] += w * b2f_lo(raw[c].x); acc[1] += w * b2f_hi(raw[c].x);
      acc[2] += w * b2f_lo(raw[c].y); acc[3] += w * b2f_hi(raw[c].y);
      acc[4] += w * b2f_lo(raw[c].z); acc[5] += w * b2f_hi(raw[c].z);
      acc[6] += w * b2f_lo(raw[c].w); acc[7] += w * b2f_hi(raw[c].w);
    }
  }

  unsigned o0 = f2bf(acc[0]) | ((unsigned)f2bf(acc[1]) << 16);
  unsigned o1 = f2bf(acc[2]) | ((unsigned)f2bf(acc[3]) << 16);
  unsigned o2 = f2bf(acc[4]) | ((unsigned)f2bf(acc[5]) << 16);
  unsigned o3 = f2bf(acc[6]) | ((unsigned)f2bf(acc[7]) << 16);
  uint4 st = {o0, o1, o2, o3};

  // staged layout for the final GEMM: tile = bq>>7, row = bq&127, stage = h, u = c0>>3
  int mtile = bq >> 7, row = bq & 127;
  size_t goff = (((size_t)(mtile * 8 + h)) * 512 + (c0 >> 3) * 128 + row) * 8;
  *(uint4*)(interS + goff) = st;
}

extern "C" void kernel_launch(void* const* d_in, const int* in_sizes, int n_in,
                              void* d_out, int out_size, void* d_ws, size_t ws_size,
                              hipStream_t stream) {
  const float* query  = (const float*)d_in[0];
  const float* refp   = (const float*)d_in[1];
  const float* inputf = (const float*)d_in[2];
  const float* Wv   = (const float*)d_in[5];
  const float* bv   = (const float*)d_in[6];
  const float* Wo   = (const float*)d_in[7];
  const float* bo   = (const float*)d_in[8];
  const float* Wa   = (const float*)d_in[9];
  const float* ba   = (const float*)d_in[10];
  const float* Wout = (const float*)d_in[11];
  const float* bout = (const float*)d_in[12];

  char* p = (char*)d_ws;
  auto alloc = [&](size_t bytes) -> char* {
    char* r = p;
    p += (bytes + 255) & ~(size_t)255;
    return r;
  };
  unsigned short* val   = (unsigned short*)alloc((size_t)MV * 256 * 2);
  unsigned short* WvS   = (unsigned short*)alloc(2 * 4096 * 8 * 2);
  unsigned short* WcS   = (unsigned short*)alloc(3 * 4096 * 8 * 2);
  unsigned short* WoS   = (unsigned short*)alloc(2 * 4096 * 8 * 2);
  float*          bcat  = (float*)alloc(384 * 4);
  float*          offattn = (float*)alloc((size_t)MQ * 384 * 4);
  unsigned short* interS = (unsigned short*)alloc((size_t)MQ * 256 * 2);

  prep_k<<<114, 256, 0, stream>>>(Wv, Wo, Wa, Wout, bo, ba, WvS, WcS, WoS, bcat);

  // value = input_flatten @ Wv + bv (fp32 A reg-staged) -> bf16 [MV,256]
  gemm3_k<true, true><<<(MV / 128) * 2, 256, 0, stream>>>(
      (const void*)inputf, WvS, bv, val, MV, 256);
  // offattn = query @ [Wo|Wa] + [bo|ba] -> fp32 [MQ,384]
  gemm3_k<true, false><<<(MQ / 128) * 3, 256, 0, stream>>>(
      (const void*)query, WcS, bcat, offattn, MQ, 384);
  // sampling -> interS (staged bf16)
  sample_k<<<MQ * 32 / 256, 256, 0, stream>>>(offattn, refp, val, interS);
  // out = interS @ Wout + bout -> fp32 d_out
  gemm3_k<false, false><<<(MQ / 128) * 2, 256, 0, stream>>>(
      (const void*)interS, WoS, bout, (float*)d_out, MQ, 256);
}